// Round 18
// baseline (106.685 us; speedup 1.0000x reference)
//
#include <hip/hip_runtime.h>
#include <hip/hip_fp16.h>

// VQC statevector simulator, v18 = v17 structure, hazard-safe ops only.
// Evidence: 4/4 single-sample kernels with inline-asm v_pk_fma_f16 + DPP
// failed (v13/14/15/17, two schedules, two block sizes, two map sets);
// 3/3 two-sample kernels with the same macros passed; plain-op kernels
// (v5/v6/v8) passed single-sample. Maps re-audited (bijective, both-side
// consistent; v10 proved bad-but-bijective maps still pass) -> suspect is
// an inline-asm->DPP hazard the compiler can't see. v18 removes BOTH: all
// butterflies in __hmul2/__hfma2/__lowhigh2highlow; lane qubits + EXPECT
// via __shfl_xor (v8/v9 class). Cost 6 VALU/pair vs 4; gain = 2 independent
// 256-thread blocks/CU (64KB LDS each) -> separate barrier domains overlap
// each other's sweep drains (v16's ~35% stall).
//
// Windows (canonical bit q = qubit q), t = 8 bits t0..t7:
//  P0: n = o | (t<<6)   -> reg o = q0-5; lane0,1 = q6,q7 (shfl); t2-t7 = q8-13
//  P1: n = (o<<8) | t   -> reg o = q8-13; lane = q0-5; wave = q6,q7
// Per layer: RXP0(q0-7) -> S1(P0->P1) -> RXP1(q8-13) -> S2(P1->P0, CNOT perm
// src=(n^(n<<1))&0x3FFF folded into read). Layer-0 perm fused into encoding.
// Maps A,B: as v17 (re-verified): A: c0->1,c1->0x82,c2->0x104,c3->0x208,
// c4->0x410,c5->0x820,c6..c11->2..0x40,c12->0x1000,c13->0x2000;
// B: c8->1,c0..c5->2..0x40,c6->0x80,c7->0x100,c9->0x202,c10->0x404,
// c11->0x808,c12->0x1010,c13->0x2000. Writes = b64 streams (0-conflict),
// reads rank-5 (2-way, free).

typedef unsigned int u32;

constexpr int NQ  = 14;
constexpr int DIM = 1 << NQ;     // 16384
constexpr int NT  = 256;         // 4 waves
constexpr int APT = DIM / NT;    // 64
constexpr int NL  = 4;

#define H2U(v) __builtin_bit_cast(u32, v)
#define U2H(v) __builtin_bit_cast(__half2, v)

// Preload N qubits' (sp,cc) of layer L starting at qubit Q0 into SGPRs.
#define PRELOAD(L, Q0, N) { _Pragma("unroll")                           \
    for (int i_ = 0; i_ < (N); ++i_) {                                  \
        uint2 w_ = wtab[(L) * NQ + (Q0) + i_];                          \
        sw[i_] = __builtin_amdgcn_readfirstlane((int)w_.x);             \
        cw[i_] = __builtin_amdgcn_readfirstlane((int)w_.y); } }

// Register butterfly on o-bit QBIT (32 pairs over 64 amps), plain HIP:
// a0' = cc*a0 + sp*swap(a1); a1' = cc*a1 + sp*swap(a0); sp=(s,-s), cc=(c,c).
#define RXQs(QBIT, I) {                                                 \
    const __half2 sp_ = U2H((u32)sw[I]), cc_ = U2H((u32)cw[I]);         \
    _Pragma("unroll")                                                   \
    for (int o = 0; o < APT; ++o) {                                     \
        if (o & (1 << (QBIT))) continue;                                \
        const int o1_ = o | (1 << (QBIT));                              \
        __half2 w0_ = __lowhigh2highlow(a[o1_]);                        \
        __half2 w1_ = __lowhigh2highlow(a[o]);                          \
        a[o]   = __hfma2(sp_, w0_, __hmul2(cc_, a[o]));                 \
        a[o1_] = __hfma2(sp_, w1_, __hmul2(cc_, a[o1_])); } }

// Lane butterfly via shfl_xor (symmetric form, all 64 amps).
#define RXS(MASK, I) {                                                  \
    const __half2 sp_ = U2H((u32)sw[I]), cc_ = U2H((u32)cw[I]);         \
    _Pragma("unroll")                                                   \
    for (int o = 0; o < APT; ++o) {                                     \
        int pi_ = __shfl_xor((int)H2U(a[o]), (MASK), 64);               \
        __half2 p_ = __lowhigh2highlow(U2H((u32)pi_));                  \
        a[o] = __hfma2(sp_, p_, __hmul2(cc_, a[o])); } }

// 8-qubit P0 block (q0-5 reg, q6,q7 lane) and 6-qubit P1 block (q8-13 reg).
#define RXP0 { RXQs(0,0) RXQs(1,1) RXQs(2,2) RXQs(3,3) RXQs(4,4)        \
               RXQs(5,5) RXS(1,6) RXS(2,7) }
#define RXP1 { RXQs(0,0) RXQs(1,1) RXQs(2,2) RXQs(3,3) RXQs(4,4) RXQs(5,5) }

// ---- sweep o-offset tables (compile-time per unrolled index) ----
#define OA1K(k) ((((k)&1)?0x82:0)^(((k)&2)?0x104:0)^(((k)&4)?0x208:0)   \
               ^ (((k)&8)?0x410:0)^(((k)&16)?0x820:0))
#define OA1R(o) ((((o)&15)<<3) | (((o)>>4)<<12))
#define OB2K(k) ((((k)&1)?0x202:0)^(((k)&2)?0x404:0)^(((k)&4)?0x808:0)  \
               ^ (((k)&8)?0x1010:0)^(((k)&16)?0x2000:0))
#define OB2R(o) ((((o) ^ ((o)<<1)) & 0x7F) << 1)

#define WS1 { _Pragma("unroll") for (int k = 0; k < 32; ++k)            \
    *reinterpret_cast<uint2*>(buf + (CA1W ^ OA1K(k))) =                 \
        make_uint2(H2U(a[2*k]), H2U(a[2*k+1])); }
#define RS1 { _Pragma("unroll") for (int o = 0; o < APT; ++o)           \
    a[o] = buf[CA1R ^ OA1R(o)]; }
#define WS2 { _Pragma("unroll") for (int k = 0; k < 32; ++k)            \
    *reinterpret_cast<uint2*>(buf + (CB2W ^ OB2K(k))) =                 \
        make_uint2(H2U(a[2*k]), H2U(a[2*k+1])); }
#define RS2 { _Pragma("unroll") for (int o = 0; o < APT; ++o)           \
    a[o] = buf[CB2R ^ OB2R(o)]; }

__global__ __launch_bounds__(NT, 2)
void vqc_kernel(const float* __restrict__ inputs,
                const float* __restrict__ weights,
                float* __restrict__ out)
{
    extern __shared__ __half2 lds[];   // buf (64KB) | wtab | itab | red
    const int t    = threadIdx.x;
    const int b    = blockIdx.x;
    const int lane = t & 63;
    const int wv   = t >> 6;           // 4 waves

    __half2* buf  = lds;
    uint2*   wtab = reinterpret_cast<uint2*>(lds + DIM);       // 56
    float2*  itab = reinterpret_cast<float2*>(wtab + 56);      // 14
    float*   red  = reinterpret_cast<float*>(itab + 14);       // 52

    const int t0 = t & 1, t1 = (t >> 1) & 1, t2 = (t >> 2) & 1, t3 = (t >> 3) & 1,
              t4 = (t >> 4) & 1, t5 = (t >> 5) & 1, t6 = (t >> 6) & 1,
              t7 = (t >> 7) & 1;

    // Thread-constant address bases (maps A,B in header).
    const int CA1W = ((t & 63) << 1) | ((t >> 6) << 12);
    const int CA1R = (t0 ? 1 : 0) ^ (t1 ? 0x82 : 0) ^ (t2 ? 0x104 : 0)
                   ^ (t3 ? 0x208 : 0) ^ (t4 ? 0x410 : 0) ^ (t5 ? 0x820 : 0)
                   ^ (t6 ? 2 : 0) ^ (t7 ? 4 : 0);
    const int CB2W = ((t & 63) << 1) | ((t >> 6) << 7);
    const int s6 = t0, s7 = t1 ^ t0, s8 = t2 ^ t1, s9 = t3 ^ t2,
              s10 = t4 ^ t3, s11 = t5 ^ t4, s12 = t6 ^ t5, s13 = t7 ^ t6;
    const int CB2R = (s6 ? 0x80 : 0) ^ (s7 ? 0x100 : 0) ^ (s8 ? 1 : 0)
                   ^ (s9 ? 0x202 : 0) ^ (s10 ? 0x404 : 0) ^ (s11 ? 0x808 : 0)
                   ^ (s12 ? 0x1010 : 0) ^ (s13 ? 0x2000 : 0);

    // Sincos tables: wave0 -> weights (sp,cc packed), wave1 -> this sample.
    if (t < NL * NQ) {
        float s_, c_;
        __sincosf(0.5f * weights[t], &s_, &c_);
        wtab[t] = make_uint2(H2U(__floats2half2_rn(s_, -s_)), H2U(__float2half2_rn(c_)));
    }
    if (t >= 64 && t < 64 + NQ) {
        float s_, c_;
        __sincosf(0.5f * inputs[b * NQ + (t - 64)], &s_, &c_);
        itab[t - 64] = make_float2(s_, c_);
    }
    __syncthreads();

    int sw[8], cw[8];
    __half2 a[APT];

    // ---- Encoding fused with layer-0 CNOT perm, into P0 registers.
    // src = (n0 ^ (n0<<1)) & 0x3FFF, n0 = o | (t<<6):
    //   src0..5 = (o^(o<<1))&0x3F, src6 = o5 ^ t0, src7..13 = t-only.
    {
        const int Tme = ((t << 6) ^ (t << 7)) & 0x3FFF;
        float base = 1.0f;
#pragma unroll
        for (int q = 7; q < NQ; ++q) {
            float2 f_ = itab[q];
            base *= ((Tme >> q) & 1) ? f_.x : f_.y;
        }
        float2 f6 = itab[6];
        float g6a = (t & 1) ? f6.x : f6.y;   // o5 = 0
        float g6b = (t & 1) ? f6.y : f6.x;   // o5 = 1
        float2 f0 = itab[0], f1 = itab[1], f2 = itab[2],
               f3 = itab[3], f4 = itab[4], f5 = itab[5];
#pragma unroll
        for (int o = 0; o < APT; ++o) {
            const int op = (o ^ (o << 1)) & 0x3F;
            float v = base * ((o & 32) ? g6b : g6a);
            v *= (op & 1)  ? f0.x : f0.y;
            v *= (op & 2)  ? f1.x : f1.y;
            v *= (op & 4)  ? f2.x : f2.y;
            v *= (op & 8)  ? f3.x : f3.y;
            v *= (op & 16) ? f4.x : f4.y;
            v *= (op & 32) ? f5.x : f5.y;
            a[o] = __floats2half2_rn(v, 0.0f);
        }
    }

    // ---- layer 0 ----
    PRELOAD(0, 0, 8);
    RXP0;
    WS1;  __syncthreads();  RS1;  __syncthreads();
    PRELOAD(0, 8, 6);
    RXP1;

    // ---- layers 1..3 ----
#pragma unroll 1
    for (int l = 1; l < NL; ++l) {
        WS2;  __syncthreads();  RS2;  __syncthreads();
        PRELOAD(l, 0, 8);
        RXP0;
        WS1;  __syncthreads();  RS1;  __syncthreads();
        PRELOAD(l, 8, 6);
        RXP1;
    }

    // ---- Z expectations from P1: lane bits = q0-5, wave bits = q6,q7,
    //      o bits = q8-13. ----
    {
        float ptot = 0.f, Sq[6] = {0, 0, 0, 0, 0, 0};
#pragma unroll
        for (int o = 0; o < APT; ++o) {
            float2 f_ = __half22float2(a[o]);
            float p_ = f_.x * f_.x + f_.y * f_.y;
            ptot += p_;
#pragma unroll
            for (int m = 0; m < 6; ++m)
                Sq[m] += ((o >> m) & 1) ? -p_ : p_;
        }
        float accL[6];
#pragma unroll
        for (int k = 0; k < 6; ++k) accL[k] = ptot;
#pragma unroll
        for (int k = 0; k < 6; ++k) {
            const int m_ = 1 << k;
#pragma unroll
            for (int j = 0; j < 6; ++j) {
                float pr_ = __shfl_xor(accL[j], m_, 64);
                if (j == k) accL[j] = ((lane >> k) & 1) ? (pr_ - accL[j]) : (accL[j] - pr_);
                else        accL[j] += pr_;
            }
            ptot += __shfl_xor(ptot, m_, 64);
#pragma unroll
            for (int j2 = 0; j2 < 6; ++j2) Sq[j2] += __shfl_xor(Sq[j2], m_, 64);
        }
        if (lane == 0) {
            red[wv * 13 + 0] = ptot;
#pragma unroll
            for (int k = 0; k < 6; ++k) red[wv * 13 + 1 + k] = accL[k];
#pragma unroll
            for (int m2 = 0; m2 < 6; ++m2) red[wv * 13 + 7 + m2] = Sq[m2];
        }
    }
    __syncthreads();

    // Cross-wave combine: q0-5 = accL, q6/q7 = wave-bit signs on ptot,
    // q8-13 = Sq.
    if (t < NQ) {
        float acc = 0.f;
#pragma unroll 1
        for (int w = 0; w < 4; ++w) {
            float v;
            if (t < 6)       v = red[w * 13 + 1 + t];
            else if (t == 6) { v = red[w * 13]; if (w & 1)        v = -v; }
            else if (t == 7) { v = red[w * 13]; if ((w >> 1) & 1) v = -v; }
            else             v = red[w * 13 + 7 + (t - 8)];
            acc += v;
        }
        out[b * NQ + t] = acc;
    }
}

extern "C" void kernel_launch(void* const* d_in, const int* in_sizes, int n_in,
                              void* d_out, int out_size, void* d_ws, size_t ws_size,
                              hipStream_t stream)
{
    const float* inputs  = (const float*)d_in[0];
    const float* weights = (const float*)d_in[1];
    float* out = (float*)d_out;

    const int Bn = in_sizes[0] / NQ;   // 1024
    const size_t shmem = DIM * sizeof(__half2)
                       + 56 * sizeof(uint2) + 14 * sizeof(float2)
                       + 52 * sizeof(float);
    vqc_kernel<<<dim3(Bn), dim3(NT), shmem, stream>>>(inputs, weights, out);
}